// Round 4
// baseline (697.947 us; speedup 1.0000x reference)
//
#include <hip/hip_runtime.h>
#include <stdint.h>

typedef __attribute__((ext_vector_type(8))) short short8;
typedef __attribute__((ext_vector_type(4))) float floatx4;

__device__ inline unsigned short f2bf(float f){
  union { float fv; unsigned int u; } v; v.fv = f;
  unsigned int u = v.u;
  unsigned int r = ((u >> 16) & 1u) + 0x7FFFu;
  return (unsigned short)((u + r) >> 16);
}

// async global->LDS, 16B per lane, dest = wave-uniform base + lane*16
__device__ __forceinline__ void async16(const void* g, void* l){
  __builtin_amdgcn_global_load_lds(
      (const __attribute__((address_space(1))) unsigned int*)g,
      (__attribute__((address_space(3))) unsigned int*)l, 16, 0, 0);
}

// counted-vmcnt barrier: keep N VMEM ops in flight across the barrier.
#define PBAR(N) do {                                              \
    asm volatile("s_waitcnt vmcnt(" #N ")" ::: "memory");          \
    __builtin_amdgcn_s_barrier();                                  \
    asm volatile("" ::: "memory");                                 \
  } while (0)

// ---------------- weight prep ----------------
__global__ void prep_w1(const float* __restrict__ w, unsigned short* __restrict__ w1p){
  int i = blockIdx.x*256 + threadIdx.x;
  if (i >= 192*192) return;
  int k = i % 192, o = i / 192;
  int cc = k >> 3, kx = k & 7;
  unsigned short v = 0;
  if (cc < 21 && kx < 7){
    int c = cc / 7, ky = cc % 7;
    v = f2bf(w[(o*3 + c)*49 + ky*7 + kx]);
  }
  w1p[i] = v;
}
__global__ void prep_w2(const float* __restrict__ w, unsigned short* __restrict__ w2p){
  int i = blockIdx.x*256 + threadIdx.x;
  if (i >= 192*9408) return;
  int k = i % 9408, o = i / 9408;
  int g = k / 192, c = k % 192;
  int ky = g / 7, kx = g % 7;
  w2p[i] = f2bf(w[((o*192 + c)*7 + ky)*7 + kx]);
}
__global__ void prep_w3(const float* __restrict__ w, unsigned short* __restrict__ w3p){
  int i = blockIdx.x*256 + threadIdx.x;
  if (i >= 768*8640) return;
  int k = i % 8640, o = i / 8640;
  int g = k / 960, c = k % 960;
  int ky = g / 3, kx = g % 3;
  w3p[i] = f2bf(w[((o*960 + c)*3 + ky)*3 + kx]);
}
__global__ void prep_zp(unsigned int* __restrict__ zp){
  zp[threadIdx.x] = 0u;  // 256 B zero page
}

// ---------------- pad+im2col-kx: x -> xh2[b][c][iy(230)][ox(56)][kx(8)] bf16 ----------------
__global__ void pad_x2(const float* __restrict__ x, unsigned short* __restrict__ xh2){
  int idx = blockIdx.x*256 + threadIdx.x;
  if (idx >= 64*3*230*56*8) return;
  int kx = idx & 7; int t = idx >> 3;
  int ox = t % 56;  t /= 56;
  int iy = t % 230; t /= 230;      // t = b*3 + c
  int row = iy - 3;
  int col = 4*ox - 3 + kx;
  unsigned short v = 0;
  if (row >= 0 && row < 224 && col >= 0 && col < 224)
    v = f2bf(x[((size_t)t*224 + row)*224 + col]);
  xh2[idx] = v;
}

// ---------------- wavelet: per 16x16 block 2D WHT / 16 ----------------
__global__ void wavelet_kernel(const float* __restrict__ x, unsigned short* __restrict__ feat){
  int blk = blockIdx.x;
  int j = blk % 14; blk /= 14;
  int i = blk % 14; blk /= 14;
  int c = blk % 3;  int b = blk / 3;
  int t = threadIdx.x;
  int u = t >> 4, v = t & 15;
  float val = x[((size_t)(b*3 + c)*224 + (i*16 + u))*224 + (j*16 + v)];
  #pragma unroll
  for (int bit = 1; bit < 64; bit <<= 1){
    float p = __shfl_xor(val, bit);
    val = (t & bit) ? (p - val) : (val + p);
  }
  __shared__ float s[256];
  #pragma unroll
  for (int bit = 64; bit < 256; bit <<= 1){
    s[t] = val; __syncthreads();
    float p = s[t ^ bit]; __syncthreads();
    val = (t & bit) ? (p - val) : (val + p);
  }
  s[t] = val; __syncthreads();
  int k = t;
  int d1 = (k>>6)&3, d2 = (k>>4)&3, d3 = (k>>2)&3, d4 = k&3;
  int mr = (d1>>1) | ((d2>>1)<<1) | ((d3>>1)<<2) | ((d4>>1)<<3);
  int mc = (d1&1)  | ((d2&1)<<1)  | ((d3&1)<<2)  | ((d4&1)<<3);
  float outv = s[mr*16 + mc] * 0.0625f;
  feat[((size_t)((b*14 + i)*14 + j))*960 + (k*3 + c)] = f2bf(outv);
}

// ---------------- conv1: dbuf glds MFMA GEMM, BM=128 BN=64 K=192 (3 iters) ----------------
__global__ __launch_bounds__(256) void conv1_gemm(const unsigned short* __restrict__ xh2,
                                                  const unsigned short* __restrict__ w1p,
                                                  const float* __restrict__ b1,
                                                  unsigned short* __restrict__ sp1){
  __shared__ unsigned short As[2][128*64], Bs[2][64*64];
  int m0 = blockIdx.x*128, n0 = blockIdx.y*64;
  int tid = threadIdx.x, wave = tid >> 6, lane = tid & 63;
  int l16 = lane & 15, quad = lane >> 4;
  int wy = wave >> 1, wx = wave & 1;
  int r8 = lane >> 3, kb = (lane & 7) ^ r8;

  int Abase[4];
  #pragma unroll
  for (int j = 0; j < 4; j++){
    int row = wave*32 + j*8 + r8;
    int m = m0 + row;
    int ox = m % 56; int t = m / 56; int oy = t % 56; int b = t / 56;
    Abase[j] = (b*690 + 4*oy)*448 + ox*8;
  }
  const unsigned short* pB0 = w1p + (n0 + wave*16 + r8)*192 + kb*8;
  const unsigned short* pB1 = pB0 + 8*192;

  int sw = l16 & 7;
  int xo0 = ((quad    ) ^ sw)*8;
  int xo1 = ((quad + 4) ^ sw)*8;
  int aoff[4];
  #pragma unroll
  for (int mt = 0; mt < 4; mt++) aoff[mt] = (wy*64 + mt*16 + l16)*64;
  int boff0 = (wx*32 + l16)*64, boff1 = boff0 + 16*64;

  floatx4 acc[4][2];
  #pragma unroll
  for (int mt = 0; mt < 4; mt++)
    #pragma unroll
    for (int nt = 0; nt < 2; nt++) acc[mt][nt] = (floatx4){0.f,0.f,0.f,0.f};

  auto stage = [&](int i, int buf){
    int cc = i*8 + kb;
    int c = (cc*147) >> 10;
    int ky = cc - 7*c;
    int koff = (c*230 + ky)*448;
    #pragma unroll
    for (int j = 0; j < 4; j++)
      async16(xh2 + Abase[j] + koff, (void*)&As[buf][(wave*32 + j*8)*64]);
    async16(pB0 + i*64, (void*)&Bs[buf][(wave*16    )*64]);
    async16(pB1 + i*64, (void*)&Bs[buf][(wave*16 + 8)*64]);
  };

  stage(0, 0);
  __syncthreads();
  #pragma unroll
  for (int i = 0; i < 3; i++){
    int buf = i & 1;
    if (i < 2) stage(i+1, buf ^ 1);
    #pragma unroll
    for (int ks = 0; ks < 2; ks++){
      int xo = ks ? xo1 : xo0;
      short8 b0 = *(const short8*)&Bs[buf][boff0 + xo];
      short8 b1 = *(const short8*)&Bs[buf][boff1 + xo];
      #pragma unroll
      for (int mt = 0; mt < 4; mt++){
        short8 a = *(const short8*)&As[buf][aoff[mt] + xo];
        acc[mt][0] = __builtin_amdgcn_mfma_f32_16x16x32_bf16(a, b0, acc[mt][0], 0, 0, 0);
        acc[mt][1] = __builtin_amdgcn_mfma_f32_16x16x32_bf16(a, b1, acc[mt][1], 0, 0, 0);
      }
    }
    __syncthreads();
  }

  #pragma unroll
  for (int mt = 0; mt < 4; mt++){
    #pragma unroll
    for (int rg = 0; rg < 4; rg++){
      int row = wy*64 + mt*16 + quad*4 + rg;
      size_t ob = (size_t)(m0 + row)*192;
      #pragma unroll
      for (int nt = 0; nt < 2; nt++){
        int nn = n0 + wx*32 + nt*16 + l16;
        sp1[ob + nn] = f2bf(acc[mt][nt][rg] + b1[nn]);
      }
    }
  }
}

// ---------------- conv2/conv3: A in LDS (3-buf, counted vmcnt), B in registers ----------------
// Block tile 64x64, wave grid 2x2 (each wave owns a 32x32 quadrant, full K —
// no end reduction). A: K-128 mega-tiles (16 KB) staged via glds with the
// granule swizzle p = gsrc ^ (row&7), 3 buffers = 48 KB -> 3 blocks/CU.
// B: L2-resident weights loaded straight to registers (8x dwordx4 per mega,
// double-buffered in two NAMED arrays). Each body issues exactly 12 VMEM ops
// (4 A-glds + 8 B-loads), so PBAR(12) at the top of iter i guarantees all of
// body i-2 (tile i's A) landed while keeping 2 bodies in flight — loads span
// barriers (T3/T4). NMEGA is even -> pairwise unroll gives static B indexing.
template<int MODE>
__global__ __launch_bounds__(256, 3) void conv_gemm(const unsigned short* __restrict__ Ain,
                                                 const unsigned short* __restrict__ Bt,
                                                 const float* __restrict__ bias,
                                                 const float* __restrict__ pos,
                                                 const unsigned short* __restrict__ zp,
                                                 void* __restrict__ outp){
  constexpr int OH  = (MODE==2) ? 14 : 7;
  constexpr int OW  = OH;
  constexpr int IH  = (MODE==2) ? 56 : 14;
  constexpr int IW  = IH;
  constexpr int Cin = (MODE==2) ? 192 : 960;
  constexpr int KW  = (MODE==2) ? 7 : 3;
  constexpr int S   = (MODE==2) ? 4 : 2;
  constexpr int P   = (MODE==2) ? 3 : 1;
  constexpr int K   = (MODE==2) ? 9408 : 8640;
  constexpr int NMEGA = (K + 127)/128;     // 74 / 68 (both even)
  constexpr int MTI = (MODE==2) ? 196 : 49;
  constexpr int GRP = (MODE==2) ? 24 : 96;

  int id = blockIdx.x;
  int g = id / GRP, rem = id % GRP;
  int mtile = g*8 + (rem & 7), ntile = rem >> 3;
  if (mtile >= MTI) return;
  int m0 = mtile*64, n0 = ntile*64;

  // 3 A-buffers, each 64 rows x 128 k (16 KB) -> 48 KB total
  __shared__ unsigned short smem[3*8192];

  int tid = threadIdx.x, wv = tid >> 6, lane = tid & 63;
  int l16 = lane & 15, quad = lane >> 4;
  int wy = wv >> 1, wx = wv & 1;

  // ---- A staging precompute: wave wv stages rows wv*16 .. wv*16+15 ----
  int lr = lane >> 4;                    // row within a 4-row glds call
  int gp = lane & 15;                    // storage granule position
  int ksoff[4], abase[4], iyb[4], ixb[4];
  #pragma unroll
  for (int j = 0; j < 4; j++){
    int r = wv*16 + j*4 + lr;            // A-tile row staged by this lane
    int gsrc = gp ^ (r & 7);             // source granule for storage slot gp
    ksoff[j] = gsrc*8;
    int m = m0 + r;
    int ox = m % OW; int t = m / OW; int oy = t % OH; int bb = t / OH;
    iyb[j] = S*oy - P; ixb[j] = S*ox - P;
    abase[j] = ((bb*IH + iyb[j])*IW + ixb[j])*Cin;
  }

  // ---- A fragment read offsets (swizzled) ----
  int aro[2], g4[4];
  #pragma unroll
  for (int mi = 0; mi < 2; mi++) aro[mi] = (wy*32 + mi*16 + l16)*128;
  #pragma unroll
  for (int kq = 0; kq < 4; kq++) g4[kq] = ((kq*4 + quad) ^ (l16 & 7))*8;

  // ---- B register-load bases: rows wx*32+ni*16+l16, 16B at k0+kq*32+quad*8 ----
  const unsigned short* bbase[2];
  #pragma unroll
  for (int ni = 0; ni < 2; ni++)
    bbase[ni] = Bt + (size_t)(n0 + wx*32 + ni*16 + l16)*K + quad*8;

  floatx4 acc[2][2];
  #pragma unroll
  for (int mi = 0; mi < 2; mi++)
    #pragma unroll
    for (int ni = 0; ni < 2; ni++) acc[mi][ni] = (floatx4){0.f,0.f,0.f,0.f};

  auto stageTo = [&](int buf, int mega){
    int k0 = mega*128;
    unsigned short* Ad = &smem[buf*8192];
    #pragma unroll
    for (int j = 0; j < 4; j++){
      int k = k0 + ksoff[j];
      int c = k % Cin;
      int tp = k / Cin;
      int ky = tp / KW, kx = tp - ky*KW;
      int iy = iyb[j] + ky, ix = ixb[j] + kx;
      bool v = ((unsigned)iy < (unsigned)IH) & ((unsigned)ix < (unsigned)IW) & (k < K);
      const unsigned short* src = v ? (Ain + abase[j] + (ky*IW + kx)*Cin + c) : zp;
      async16(src, (void*)&Ad[(wv*16 + j*4)*128]);
    }
  };

  auto loadB = [&](short8 (&dst)[2][4], int k0){
    #pragma unroll
    for (int ni = 0; ni < 2; ni++)
      #pragma unroll
      for (int kq = 0; kq < 4; kq++)
        dst[ni][kq] = *(const short8*)(bbase[ni] + k0 + kq*32);
  };

  auto compute = [&](int buf, const short8 (&bb)[2][4]){
    const unsigned short* Ab = &smem[buf*8192];
    short8 a[2][4];
    #pragma unroll
    for (int mi = 0; mi < 2; mi++)
      #pragma unroll
      for (int kq = 0; kq < 4; kq++)
        a[mi][kq] = *(const short8*)&Ab[aro[mi] + g4[kq]];
    #pragma unroll
    for (int kq = 0; kq < 4; kq++)
      #pragma unroll
      for (int mi = 0; mi < 2; mi++)
        #pragma unroll
        for (int ni = 0; ni < 2; ni++)
          acc[mi][ni] = __builtin_amdgcn_mfma_f32_16x16x32_bf16(a[mi][kq], bb[ni][kq], acc[mi][ni], 0, 0, 0);
  };

  short8 b0r[2][4], b1r[2][4];

  // prologue: tile 0 fully landed (one-time drain), then enter counted pipeline
  stageTo(0, 0);
  __syncthreads();
  stageTo(1, 1);
  loadB(b0r, 0);

  int cur = 0;                                  // buffer holding mega i
  for (int i = 0; i < NMEGA; i += 2){
    int s0b = cur + 2; if (s0b >= 3) s0b -= 3;
    PBAR(12);
    stageTo(s0b, i+2);
    loadB(b1r, (i+1 < NMEGA ? i+1 : NMEGA-1)*128);
    compute(cur, b0r);
    int c1 = cur + 1; if (c1 >= 3) c1 -= 3;
    int s1b = s0b + 1; if (s1b >= 3) s1b -= 3;
    PBAR(12);
    stageTo(s1b, i+3);
    loadB(b0r, (i+2 < NMEGA ? i+2 : NMEGA-1)*128);
    compute(c1, b1r);
    cur = c1 + 1; if (cur >= 3) cur -= 3;
  }

  // drain LDS-DMA before workgroup teardown (trailing zp stages in flight)
  asm volatile("s_waitcnt vmcnt(0)" ::: "memory");

  // ---- epilogue: each wave stores its 32x32 quadrant directly ----
  #pragma unroll
  for (int mi = 0; mi < 2; mi++){
    #pragma unroll
    for (int rg = 0; rg < 4; rg++){
      int row = wy*32 + mi*16 + quad*4 + rg;
      int mm = m0 + row;
      #pragma unroll
      for (int ni = 0; ni < 2; ni++){
        int nn = n0 + wx*32 + ni*16 + l16;
        float v = acc[mi][ni][rg] + bias[nn];
        if (MODE == 2){
          ((unsigned short*)outp)[(size_t)mm*960 + 768 + nn] = f2bf(v);
        } else {
          int b2 = mm / 49;
          int tt = mm - b2*49;
          v += pos[(size_t)(1 + tt)*768 + nn];
          ((float*)outp)[((size_t)(mm + b2 + 1))*768 + nn] = v;
        }
      }
    }
  }
}

// ---------------- cls row ----------------
__global__ void cls_kernel(const float* __restrict__ cls, const float* __restrict__ pos,
                           float* __restrict__ out){
  int i = blockIdx.x*256 + threadIdx.x;
  if (i >= 64*768) return;
  int e = i % 768, b = i / 768;
  out[(size_t)(b*50)*768 + e] = cls[e] + pos[e];
}

extern "C" void kernel_launch(void* const* d_in, const int* in_sizes, int n_in,
                              void* d_out, int out_size, void* d_ws, size_t ws_size,
                              hipStream_t stream){
  (void)in_sizes; (void)n_in; (void)out_size;
  const float* x    = (const float*)d_in[0];
  const float* w_s1 = (const float*)d_in[1];
  const float* b_s1 = (const float*)d_in[2];
  const float* w_s2 = (const float*)d_in[3];
  const float* b_s2 = (const float*)d_in[4];
  const float* w_p  = (const float*)d_in[5];
  const float* b_p  = (const float*)d_in[6];
  const float* cls  = (const float*)d_in[7];
  const float* pos  = (const float*)d_in[8];
  float* out = (float*)d_out;

  char* ws = (char*)d_ws;
  if (ws_size < 118235136u) return;
  unsigned short* w1p  = (unsigned short*)(ws + 0);
  unsigned short* sp1  = (unsigned short*)(ws + 131072);
  unsigned short* zp   = (unsigned short*)(ws + 77201408u);
  unsigned short* w2p  = (unsigned short*)(ws + 77266944u);
  unsigned short* w3p  = (unsigned short*)(ws + 80879616u);
  unsigned short* feat = (unsigned short*)(ws + 94150656u);
  unsigned short* xh2  = (unsigned short*)(ws + 77266944u);

  prep_w1<<<(192*192 + 255)/256, 256, 0, stream>>>(w_s1, w1p);
  pad_x2<<<(64*3*230*56*8)/256, 256, 0, stream>>>(x, xh2);
  conv1_gemm<<<dim3(1568, 3), 256, 0, stream>>>(xh2, w1p, b_s1, sp1);
  prep_w2<<<(192*9408 + 255)/256, 256, 0, stream>>>(w_s2, w2p);
  prep_w3<<<(768*8640 + 255)/256, 256, 0, stream>>>(w_p, w3p);
  prep_zp<<<1, 64, 0, stream>>>((unsigned int*)zp);
  wavelet_kernel<<<64*3*14*14, 256, 0, stream>>>(x, feat);
  conv_gemm<2><<<600, 256, 0, stream>>>(sp1, w2p, b_s2, nullptr, zp, (void*)feat);
  conv_gemm<3><<<672, 256, 0, stream>>>(feat, w3p, b_p, pos, zp, (void*)out);
  cls_kernel<<<(64*768 + 255)/256, 256, 0, stream>>>(cls, pos, out);
}

// Round 5
// 432.887 us; speedup vs baseline: 1.6123x; 1.6123x over previous
//
#include <hip/hip_runtime.h>
#include <stdint.h>

typedef __attribute__((ext_vector_type(8))) short short8;
typedef __attribute__((ext_vector_type(4))) float floatx4;

__device__ inline unsigned short f2bf(float f){
  union { float fv; unsigned int u; } v; v.fv = f;
  unsigned int u = v.u;
  unsigned int r = ((u >> 16) & 1u) + 0x7FFFu;
  return (unsigned short)((u + r) >> 16);
}

// async global->LDS, 16B per lane, dest = wave-uniform base + lane*16
__device__ __forceinline__ void async16(const void* g, void* l){
  __builtin_amdgcn_global_load_lds(
      (const __attribute__((address_space(1))) unsigned int*)g,
      (__attribute__((address_space(3))) unsigned int*)l, 16, 0, 0);
}

// s_waitcnt vmcnt(N) with memory clobber (pins glds/ds ops), then a proper
// convergent barrier, then another compiler fence so LDS reads can't hoist
// above the barrier. __syncthreads would drain vmcnt(0) — defeats the pipeline.
#define PBAR(N) do {                                              \
    asm volatile("s_waitcnt vmcnt(" #N ")" ::: "memory");          \
    __builtin_amdgcn_s_barrier();                                  \
    asm volatile("" ::: "memory");                                 \
  } while (0)

// ---------------- weight prep ----------------
__global__ void prep_w1(const float* __restrict__ w, unsigned short* __restrict__ w1p){
  int i = blockIdx.x*256 + threadIdx.x;
  if (i >= 192*192) return;
  int k = i % 192, o = i / 192;
  int cc = k >> 3, kx = k & 7;
  unsigned short v = 0;
  if (cc < 21 && kx < 7){
    int c = cc / 7, ky = cc % 7;
    v = f2bf(w[(o*3 + c)*49 + ky*7 + kx]);
  }
  w1p[i] = v;
}
__global__ void prep_w2(const float* __restrict__ w, unsigned short* __restrict__ w2p){
  int i = blockIdx.x*256 + threadIdx.x;
  if (i >= 192*9408) return;
  int k = i % 9408, o = i / 9408;
  int g = k / 192, c = k % 192;
  int ky = g / 7, kx = g % 7;
  w2p[i] = f2bf(w[((o*192 + c)*7 + ky)*7 + kx]);
}
__global__ void prep_w3(const float* __restrict__ w, unsigned short* __restrict__ w3p){
  int i = blockIdx.x*256 + threadIdx.x;
  if (i >= 768*8640) return;
  int k = i % 8640, o = i / 8640;
  int g = k / 960, c = k % 960;
  int ky = g / 3, kx = g % 3;
  w3p[i] = f2bf(w[((o*960 + c)*3 + ky)*3 + kx]);
}
__global__ void prep_zp(unsigned int* __restrict__ zp){
  zp[threadIdx.x] = 0u;  // 256 B zero page
}

// ---------------- pad+im2col-kx: x -> xh2[b][c][iy(230)][ox(56)][kx(8)] bf16 ----------------
__global__ void pad_x2(const float* __restrict__ x, unsigned short* __restrict__ xh2){
  int idx = blockIdx.x*256 + threadIdx.x;
  if (idx >= 64*3*230*56*8) return;
  int kx = idx & 7; int t = idx >> 3;
  int ox = t % 56;  t /= 56;
  int iy = t % 230; t /= 230;      // t = b*3 + c
  int row = iy - 3;
  int col = 4*ox - 3 + kx;
  unsigned short v = 0;
  if (row >= 0 && row < 224 && col >= 0 && col < 224)
    v = f2bf(x[((size_t)t*224 + row)*224 + col]);
  xh2[idx] = v;
}

// ---------------- wavelet: per 16x16 block 2D WHT / 16 ----------------
__global__ void wavelet_kernel(const float* __restrict__ x, unsigned short* __restrict__ feat){
  int blk = blockIdx.x;
  int j = blk % 14; blk /= 14;
  int i = blk % 14; blk /= 14;
  int c = blk % 3;  int b = blk / 3;
  int t = threadIdx.x;
  int u = t >> 4, v = t & 15;
  float val = x[((size_t)(b*3 + c)*224 + (i*16 + u))*224 + (j*16 + v)];
  #pragma unroll
  for (int bit = 1; bit < 64; bit <<= 1){
    float p = __shfl_xor(val, bit);
    val = (t & bit) ? (p - val) : (val + p);
  }
  __shared__ float s[256];
  #pragma unroll
  for (int bit = 64; bit < 256; bit <<= 1){
    s[t] = val; __syncthreads();
    float p = s[t ^ bit]; __syncthreads();
    val = (t & bit) ? (p - val) : (val + p);
  }
  s[t] = val; __syncthreads();
  int k = t;
  int d1 = (k>>6)&3, d2 = (k>>4)&3, d3 = (k>>2)&3, d4 = k&3;
  int mr = (d1>>1) | ((d2>>1)<<1) | ((d3>>1)<<2) | ((d4>>1)<<3);
  int mc = (d1&1)  | ((d2&1)<<1)  | ((d3&1)<<2)  | ((d4&1)<<3);
  float outv = s[mr*16 + mc] * 0.0625f;
  feat[((size_t)((b*14 + i)*14 + j))*960 + (k*3 + c)] = f2bf(outv);
}

// ---------------- conv1: dbuf glds MFMA GEMM, BM=128 BN=64 K=192 (3 iters) ----------------
__global__ __launch_bounds__(256) void conv1_gemm(const unsigned short* __restrict__ xh2,
                                                  const unsigned short* __restrict__ w1p,
                                                  const float* __restrict__ b1,
                                                  unsigned short* __restrict__ sp1){
  __shared__ unsigned short As[2][128*64], Bs[2][64*64];
  int m0 = blockIdx.x*128, n0 = blockIdx.y*64;
  int tid = threadIdx.x, wave = tid >> 6, lane = tid & 63;
  int l16 = lane & 15, quad = lane >> 4;
  int wy = wave >> 1, wx = wave & 1;
  int r8 = lane >> 3, kb = (lane & 7) ^ r8;

  int Abase[4];
  #pragma unroll
  for (int j = 0; j < 4; j++){
    int row = wave*32 + j*8 + r8;
    int m = m0 + row;
    int ox = m % 56; int t = m / 56; int oy = t % 56; int b = t / 56;
    Abase[j] = (b*690 + 4*oy)*448 + ox*8;
  }
  const unsigned short* pB0 = w1p + (n0 + wave*16 + r8)*192 + kb*8;
  const unsigned short* pB1 = pB0 + 8*192;

  int sw = l16 & 7;
  int xo0 = ((quad    ) ^ sw)*8;
  int xo1 = ((quad + 4) ^ sw)*8;
  int aoff[4];
  #pragma unroll
  for (int mt = 0; mt < 4; mt++) aoff[mt] = (wy*64 + mt*16 + l16)*64;
  int boff0 = (wx*32 + l16)*64, boff1 = boff0 + 16*64;

  floatx4 acc[4][2];
  #pragma unroll
  for (int mt = 0; mt < 4; mt++)
    #pragma unroll
    for (int nt = 0; nt < 2; nt++) acc[mt][nt] = (floatx4){0.f,0.f,0.f,0.f};

  auto stage = [&](int i, int buf){
    int cc = i*8 + kb;
    int c = (cc*147) >> 10;
    int ky = cc - 7*c;
    int koff = (c*230 + ky)*448;
    #pragma unroll
    for (int j = 0; j < 4; j++)
      async16(xh2 + Abase[j] + koff, (void*)&As[buf][(wave*32 + j*8)*64]);
    async16(pB0 + i*64, (void*)&Bs[buf][(wave*16    )*64]);
    async16(pB1 + i*64, (void*)&Bs[buf][(wave*16 + 8)*64]);
  };

  stage(0, 0);
  __syncthreads();
  #pragma unroll
  for (int i = 0; i < 3; i++){
    int buf = i & 1;
    if (i < 2) stage(i+1, buf ^ 1);
    #pragma unroll
    for (int ks = 0; ks < 2; ks++){
      int xo = ks ? xo1 : xo0;
      short8 b0 = *(const short8*)&Bs[buf][boff0 + xo];
      short8 b1 = *(const short8*)&Bs[buf][boff1 + xo];
      #pragma unroll
      for (int mt = 0; mt < 4; mt++){
        short8 a = *(const short8*)&As[buf][aoff[mt] + xo];
        acc[mt][0] = __builtin_amdgcn_mfma_f32_16x16x32_bf16(a, b0, acc[mt][0], 0, 0, 0);
        acc[mt][1] = __builtin_amdgcn_mfma_f32_16x16x32_bf16(a, b1, acc[mt][1], 0, 0, 0);
      }
    }
    __syncthreads();
  }

  #pragma unroll
  for (int mt = 0; mt < 4; mt++){
    #pragma unroll
    for (int rg = 0; rg < 4; rg++){
      int row = wy*64 + mt*16 + quad*4 + rg;
      size_t ob = (size_t)(m0 + row)*192;
      #pragma unroll
      for (int nt = 0; nt < 2; nt++){
        int nn = n0 + wx*32 + nt*16 + l16;
        sp1[ob + nn] = f2bf(acc[mt][nt][rg] + b1[nn]);
      }
    }
  }
}

// ---------------- conv2/conv3: round-0 pipeline, wave (kh,nh) K/N-split ----------------
// Staging, LDS layout, swizzle, 3 buffers, PBAR(4) pipeline: byte-identical to
// the verified round-0 kernel (0 bank conflicts, FETCH ~80MB). Only the wave->
// work map changes: wave (kh = wv>>1, nh = wv&1) computes ALL 64 rows x its
// 32-col half over its K-32 half of each K-64 body (4 A-frags + 2 B-frags =
// 6KB reads/wave/body vs 8KB before => block reads 24KB vs 32KB). Same 8 MFMA
// per wave per body, acc[4][2]. One 2-way K-partial reduction at the end
// through the then-dead LDS buffers (stride-33 pad); kh=0 waves store.
template<int MODE>
__global__ __launch_bounds__(256) void conv_gemm(const unsigned short* __restrict__ Ain,
                                                 const unsigned short* __restrict__ Bt,
                                                 const float* __restrict__ bias,
                                                 const float* __restrict__ pos,
                                                 const unsigned short* __restrict__ zp,
                                                 void* __restrict__ outp){
  constexpr int OH  = (MODE==2) ? 14 : 7;
  constexpr int OW  = OH;
  constexpr int IH  = (MODE==2) ? 56 : 14;
  constexpr int IW  = IH;
  constexpr int Cin = (MODE==2) ? 192 : 960;
  constexpr int KW  = (MODE==2) ? 7 : 3;
  constexpr int S   = (MODE==2) ? 4 : 2;
  constexpr int P   = (MODE==2) ? 3 : 1;
  constexpr int K   = (MODE==2) ? 9408 : 8640;
  constexpr int NIT = K/64;
  constexpr int MTI = (MODE==2) ? 196 : 49;
  constexpr int GRP = (MODE==2) ? 24 : 96;

  int id = blockIdx.x;
  int g = id / GRP, rem = id % GRP;
  int mtile = g*8 + (rem & 7), ntile = rem >> 3;
  if (mtile >= MTI) return;
  int m0 = mtile*64, n0 = ntile*64;

  __shared__ unsigned short As[3][64*64], Bs[3][64*64];
  int tid = threadIdx.x, wave = tid >> 6, lane = tid & 63;
  int l16 = lane & 15, quad = lane >> 4;
  int kh = wave >> 1, nh = wave & 1;

  int r8 = lane >> 3, kb = (lane & 7) ^ r8;
  int rA0 = wave*16 + r8, rA1 = rA0 + 8;

  int m_0 = m0 + rA0;
  int ox0 = m_0 % OW; int t0 = m_0 / OW; int oy0 = t0 % OH; int bb0 = t0 / OH;
  int iyb0 = S*oy0 - P, ixb0 = S*ox0 - P;
  int abase0 = ((bb0*IH + iyb0)*IW + ixb0)*Cin + kb*8;
  int m_1 = m0 + rA1;
  int ox1 = m_1 % OW; int t1 = m_1 / OW; int oy1 = t1 % OH; int bb1 = t1 / OH;
  int iyb1 = S*oy1 - P, ixb1 = S*ox1 - P;
  int abase1 = ((bb1*IH + iyb1)*IW + ixb1)*Cin + kb*8;

  const unsigned short* pB0 = Bt + (size_t)(n0 + rA0)*K + kb*8;
  const unsigned short* pB1 = Bt + (size_t)(n0 + rA1)*K + kb*8;

  int sw = l16 & 7;
  int xo = ((kh*4 + quad) ^ sw)*8;      // wave-fixed K-32 half (kh=0: xo0, kh=1: xo1)
  int aoff[4];
  #pragma unroll
  for (int mt = 0; mt < 4; mt++) aoff[mt] = (mt*16 + l16)*64;
  int boff0 = (nh*32      + l16)*64;
  int boff1 = (nh*32 + 16 + l16)*64;

  floatx4 acc[4][2];
  #pragma unroll
  for (int mt = 0; mt < 4; mt++)
    #pragma unroll
    for (int nt = 0; nt < 2; nt++) acc[mt][nt] = (floatx4){0.f,0.f,0.f,0.f};

  int c0 = 0, ky = 0, kx = 0, k0n = 0;

  auto stage = [&](int buf){
    int koff = (ky*IW + kx)*Cin + c0;
    int iy0 = iyb0 + ky, ix0 = ixb0 + kx;
    int iy1 = iyb1 + ky, ix1 = ixb1 + kx;
    const unsigned short* pa0 = ((unsigned)iy0 < (unsigned)IH && (unsigned)ix0 < (unsigned)IW)
                                ? (Ain + (abase0 + koff)) : zp;
    const unsigned short* pa1 = ((unsigned)iy1 < (unsigned)IH && (unsigned)ix1 < (unsigned)IW)
                                ? (Ain + (abase1 + koff)) : zp;
    async16(pa0, (void*)&As[buf][(wave*16    )*64]);
    async16(pa1, (void*)&As[buf][(wave*16 + 8)*64]);
    async16(pB0 + k0n, (void*)&Bs[buf][(wave*16    )*64]);
    async16(pB1 + k0n, (void*)&Bs[buf][(wave*16 + 8)*64]);
    k0n += 64;
    c0 += 64;
    if (c0 == Cin){ c0 = 0; kx++; if (kx == KW){ kx = 0; ky++; } }
  };

  auto compute = [&](int buf){
    short8 b0 = *(const short8*)&Bs[buf][boff0 + xo];
    short8 b1 = *(const short8*)&Bs[buf][boff1 + xo];
    short8 a0 = *(const short8*)&As[buf][aoff[0] + xo];
    short8 a1 = *(const short8*)&As[buf][aoff[1] + xo];
    short8 a2 = *(const short8*)&As[buf][aoff[2] + xo];
    short8 a3 = *(const short8*)&As[buf][aoff[3] + xo];
    acc[0][0] = __builtin_amdgcn_mfma_f32_16x16x32_bf16(a0, b0, acc[0][0], 0, 0, 0);
    acc[0][1] = __builtin_amdgcn_mfma_f32_16x16x32_bf16(a0, b1, acc[0][1], 0, 0, 0);
    acc[1][0] = __builtin_amdgcn_mfma_f32_16x16x32_bf16(a1, b0, acc[1][0], 0, 0, 0);
    acc[1][1] = __builtin_amdgcn_mfma_f32_16x16x32_bf16(a1, b1, acc[1][1], 0, 0, 0);
    acc[2][0] = __builtin_amdgcn_mfma_f32_16x16x32_bf16(a2, b0, acc[2][0], 0, 0, 0);
    acc[2][1] = __builtin_amdgcn_mfma_f32_16x16x32_bf16(a2, b1, acc[2][1], 0, 0, 0);
    acc[3][0] = __builtin_amdgcn_mfma_f32_16x16x32_bf16(a3, b0, acc[3][0], 0, 0, 0);
    acc[3][1] = __builtin_amdgcn_mfma_f32_16x16x32_bf16(a3, b1, acc[3][1], 0, 0, 0);
  };

  // depth-2 pipeline over 3 buffers; 8 glds in flight at each barrier.
  // iter i: [vmcnt(4); barrier] -> tile i landed everywhere, tile i+1 in
  // flight -> stage(i+2) (overwrites buf consumed at iter i-1, all waves past
  // barrier) -> compute(i).
  stage(0); stage(1);
  int bc = 0;                       // buf of tile i
  for (int i = 0; i < NIT - 2; i++){
    PBAR(4);
    int bn = bc + 2; if (bn >= 3) bn -= 3;
    stage(bn);
    compute(bc);
    bc = (bc == 2) ? 0 : bc + 1;
  }
  PBAR(4);
  compute(bc);
  bc = (bc == 2) ? 0 : bc + 1;
  PBAR(0);
  compute(bc);

  // ---- 2-way K-partial reduction through the dead staging LDS ----
  __syncthreads();                      // all waves done reading As/Bs
  float* red = (float*)As;              // 2 regions of 64x33 floats (16.5KB < 24KB)
  if (kh == 1){
    #pragma unroll
    for (int mt = 0; mt < 4; mt++)
      #pragma unroll
      for (int nt = 0; nt < 2; nt++)
        #pragma unroll
        for (int rg = 0; rg < 4; rg++){
          int row = mt*16 + quad*4 + rg;
          red[nh*2112 + row*33 + nt*16 + l16] = acc[mt][nt][rg];
        }
  }
  __syncthreads();
  if (kh == 0){
    #pragma unroll
    for (int mt = 0; mt < 4; mt++){
      #pragma unroll
      for (int rg = 0; rg < 4; rg++){
        int row = mt*16 + quad*4 + rg;
        int mm = m0 + row;
        #pragma unroll
        for (int nt = 0; nt < 2; nt++){
          int nn = n0 + nh*32 + nt*16 + l16;
          float v = acc[mt][nt][rg] + red[nh*2112 + row*33 + nt*16 + l16] + bias[nn];
          if (MODE == 2){
            ((unsigned short*)outp)[(size_t)mm*960 + 768 + nn] = f2bf(v);
          } else {
            int b2 = mm / 49;
            int tt = mm - b2*49;
            v += pos[(size_t)(1 + tt)*768 + nn];
            ((float*)outp)[((size_t)(mm + b2 + 1))*768 + nn] = v;
          }
        }
      }
    }
  }
}

// ---------------- cls row ----------------
__global__ void cls_kernel(const float* __restrict__ cls, const float* __restrict__ pos,
                           float* __restrict__ out){
  int i = blockIdx.x*256 + threadIdx.x;
  if (i >= 64*768) return;
  int e = i % 768, b = i / 768;
  out[(size_t)(b*50)*768 + e] = cls[e] + pos[e];
}

extern "C" void kernel_launch(void* const* d_in, const int* in_sizes, int n_in,
                              void* d_out, int out_size, void* d_ws, size_t ws_size,
                              hipStream_t stream){
  (void)in_sizes; (void)n_in; (void)out_size;
  const float* x    = (const float*)d_in[0];
  const float* w_s1 = (const float*)d_in[1];
  const float* b_s1 = (const float*)d_in[2];
  const float* w_s2 = (const float*)d_in[3];
  const float* b_s2 = (const float*)d_in[4];
  const float* w_p  = (const float*)d_in[5];
  const float* b_p  = (const float*)d_in[6];
  const float* cls  = (const float*)d_in[7];
  const float* pos  = (const float*)d_in[8];
  float* out = (float*)d_out;

  char* ws = (char*)d_ws;
  // ws layout: see round-3 notes (unchanged)
  if (ws_size < 118235136u) return;
  unsigned short* w1p  = (unsigned short*)(ws + 0);
  unsigned short* sp1  = (unsigned short*)(ws + 131072);
  unsigned short* zp   = (unsigned short*)(ws + 77201408u);
  unsigned short* w2p  = (unsigned short*)(ws + 77266944u);
  unsigned short* w3p  = (unsigned short*)(ws + 80879616u);
  unsigned short* feat = (unsigned short*)(ws + 94150656u);
  unsigned short* xh2  = (unsigned short*)(ws + 77266944u);

  prep_w1<<<(192*192 + 255)/256, 256, 0, stream>>>(w_s1, w1p);
  pad_x2<<<(64*3*230*56*8)/256, 256, 0, stream>>>(x, xh2);
  conv1_gemm<<<dim3(1568, 3), 256, 0, stream>>>(xh2, w1p, b_s1, sp1);
  prep_w2<<<(192*9408 + 255)/256, 256, 0, stream>>>(w_s2, w2p);
  prep_w3<<<(768*8640 + 255)/256, 256, 0, stream>>>(w_p, w3p);
  prep_zp<<<1, 64, 0, stream>>>((unsigned int*)zp);
  wavelet_kernel<<<64*3*14*14, 256, 0, stream>>>(x, feat);
  conv_gemm<2><<<600, 256, 0, stream>>>(sp1, w2p, b_s2, nullptr, zp, (void*)feat);
  conv_gemm<3><<<672, 256, 0, stream>>>(feat, w3p, b_p, pos, zp, (void*)out);
  cls_kernel<<<(64*768 + 255)/256, 256, 0, stream>>>(cls, pos, out);
}